// Round 5
// baseline (823.008 us; speedup 1.0000x reference)
//
#include <hip/hip_runtime.h>
#include <hip/hip_bf16.h>
#include <cstdint>
#include <cstddef>

// Problem constants
#define B_    8192
#define IN_   4096
#define OUT_  4096
#define F_    16
#define FS_   256
#define COMP_ 1024
#define KBIG  (IN_ + COMP_)   // 5120 fused-K

typedef unsigned short ushort_t;
typedef __attribute__((ext_vector_type(8))) short short8;   // 8 bf16 (4 VGPRs)
typedef __attribute__((ext_vector_type(4))) float f32x4;    // MFMA acc

// fp32 -> bf16 round-to-nearest-even (finite inputs only)
__device__ __forceinline__ ushort_t f2b(float f) {
  unsigned u = __float_as_uint(f);
  u += 0x7fffu + ((u >> 16) & 1u);
  return (ushort_t)(u >> 16);
}

// async global->LDS, 16B per lane; lds dest = wave-uniform base + lane*16
__device__ __forceinline__ void gll16(const void* gp, void* lp) {
  __builtin_amdgcn_global_load_lds(
      (const __attribute__((address_space(1))) unsigned int*)gp,
      (__attribute__((address_space(3))) unsigned int*)lp, 16, 0, 0);
}

// ---------------------------------------------------------------------------
// K1: per-row selector scores -> softmax -> write y (gated) into A_big cols
// [0,4096) and m = x - y into Mbuf, both bf16. One row per 256-thread block.
// ---------------------------------------------------------------------------
__global__ void __launch_bounds__(256) gate_kernel(
    const float* __restrict__ x, const float* __restrict__ sel,
    ushort_t* __restrict__ Abig, ushort_t* __restrict__ Mbuf) {
  const int row = blockIdx.x;
  const int t = threadIdx.x;            // 0..255, 16 elems each
  const float* xr = x + (size_t)row * IN_ + t * 16;
  float4 xv0 = ((const float4*)xr)[0];
  float4 xv1 = ((const float4*)xr)[1];
  float4 xv2 = ((const float4*)xr)[2];
  float4 xv3 = ((const float4*)xr)[3];

  const int f = t >> 4;                 // fragment of this thread
  const int sub = t & 15;
  const float* sp = sel + f * FS_ + sub * 16;
  float4 s0 = ((const float4*)sp)[0];
  float4 s1 = ((const float4*)sp)[1];
  float4 s2 = ((const float4*)sp)[2];
  float4 s3 = ((const float4*)sp)[3];

  float dot = xv0.x * s0.x + xv0.y * s0.y + xv0.z * s0.z + xv0.w * s0.w
            + xv1.x * s1.x + xv1.y * s1.y + xv1.z * s1.z + xv1.w * s1.w
            + xv2.x * s2.x + xv2.y * s2.y + xv2.z * s2.z + xv2.w * s2.w
            + xv3.x * s3.x + xv3.y * s3.y + xv3.z * s3.z + xv3.w * s3.w;

  // reduce across the 16 lanes of this fragment (lane groups are 16-aligned)
  #pragma unroll
  for (int off = 8; off; off >>= 1) dot += __shfl_xor(dot, off, 64);

  __shared__ float sc[F_];
  if (sub == 0) sc[f] = dot;
  __syncthreads();

  float mx = sc[0];
  #pragma unroll
  for (int i = 1; i < F_; ++i) mx = fmaxf(mx, sc[i]);
  float sum = 0.f;
  #pragma unroll
  for (int i = 0; i < F_; ++i) sum += __expf(sc[i] - mx);
  const float p = __expf(sc[f] - mx) / sum;

  float xs[16] = {xv0.x, xv0.y, xv0.z, xv0.w, xv1.x, xv1.y, xv1.z, xv1.w,
                  xv2.x, xv2.y, xv2.z, xv2.w, xv3.x, xv3.y, xv3.z, xv3.w};
  union { ushort_t u[8]; uint4 v; } a0, a1, m0, m1;
  #pragma unroll
  for (int j = 0; j < 8; ++j) {
    float y0 = xs[j] * p;
    float y1 = xs[8 + j] * p;
    a0.u[j] = f2b(y0);
    a1.u[j] = f2b(y1);
    m0.u[j] = f2b(xs[j] - y0);
    m1.u[j] = f2b(xs[8 + j] - y1);
  }
  ushort_t* ap = Abig + (size_t)row * KBIG + t * 16;
  *(uint4*)ap = a0.v;
  *(uint4*)(ap + 8) = a1.v;
  ushort_t* mp = Mbuf + (size_t)row * IN_ + t * 16;
  *(uint4*)mp = m0.v;
  *(uint4*)(mp + 8) = m1.v;
}

// ---------------------------------------------------------------------------
// K2a: expert_weights [IN][OUT] fp32 -> B_big[o][k] bf16 (transposed).
// 64x64 tile via LDS; pad 65 -> <=2-way banking (free).
// ---------------------------------------------------------------------------
__global__ void __launch_bounds__(256) conv_expertT(
    const float* __restrict__ We, ushort_t* __restrict__ Bbig) {
  __shared__ float tile[64][65];
  const int k0 = blockIdx.x * 64;
  const int o0 = blockIdx.y * 64;
  const int t = threadIdx.x;
  const int kr = t >> 4;      // 0..15
  const int oq = t & 15;      // 0..15, float4 column
  #pragma unroll
  for (int rr = 0; rr < 4; ++rr) {
    int k = rr * 16 + kr;
    float4 v = *(const float4*)(We + (size_t)(k0 + k) * OUT_ + o0 + oq * 4);
    tile[k][oq * 4 + 0] = v.x;
    tile[k][oq * 4 + 1] = v.y;
    tile[k][oq * 4 + 2] = v.z;
    tile[k][oq * 4 + 3] = v.w;
  }
  __syncthreads();
  const int kc = t & 7;       // 16B k-chunk
  #pragma unroll
  for (int rr = 0; rr < 2; ++rr) {
    int o = rr * 32 + (t >> 3);
    union { ushort_t u[8]; uint4 v; } w;
    #pragma unroll
    for (int j = 0; j < 8; ++j) w.u[j] = f2b(tile[kc * 8 + j][o]);
    *(uint4*)(Bbig + (size_t)(o0 + o) * KBIG + k0 + kc * 8) = w.v;
  }
}

// K2bc (merged): W_net [OUT][COMP] -> B_big[o][4096+c] bf16  AND
//                W_comp [COMP][IN] -> bf16 flat. 8 elems/thread each.
__global__ void __launch_bounds__(256) conv_nc(
    const float* __restrict__ Wnet, const float* __restrict__ Wc,
    ushort_t* __restrict__ Bbig, ushort_t* __restrict__ Wcb) {
  int tid = blockIdx.x * 256 + threadIdx.x;
  const int NETT = (OUT_ * COMP_) / 8;          // 524288 threads for W_net
  if (tid < NETT) {
    int base = tid * 8;
    int o = base >> 10;
    int c = base & (COMP_ - 1);
    float4 v0 = ((const float4*)(Wnet + base))[0];
    float4 v1 = ((const float4*)(Wnet + base))[1];
    union { ushort_t u[8]; uint4 v; } w;
    w.u[0] = f2b(v0.x); w.u[1] = f2b(v0.y); w.u[2] = f2b(v0.z); w.u[3] = f2b(v0.w);
    w.u[4] = f2b(v1.x); w.u[5] = f2b(v1.y); w.u[6] = f2b(v1.z); w.u[7] = f2b(v1.w);
    *(uint4*)(Bbig + (size_t)o * KBIG + IN_ + c) = w.v;
  } else {
    int base = (tid - NETT) * 8;                // COMP_*IN_/8 threads
    float4 v0 = ((const float4*)(Wc + base))[0];
    float4 v1 = ((const float4*)(Wc + base))[1];
    union { ushort_t u[8]; uint4 v; } w;
    w.u[0] = f2b(v0.x); w.u[1] = f2b(v0.y); w.u[2] = f2b(v0.z); w.u[3] = f2b(v0.w);
    w.u[4] = f2b(v1.x); w.u[5] = f2b(v1.y); w.u[6] = f2b(v1.z); w.u[7] = f2b(v1.w);
    *(uint4*)(Wcb + base) = w.v;
  }
}

// split-K reduce for the small GEMM: compressed = p0 + p1 -> bf16 into
// A_big cols [4096,5120). float4 reads, uint2 (4x bf16) writes.
__global__ void __launch_bounds__(256) reduce_split(
    const float* __restrict__ p0, const float* __restrict__ p1,
    ushort_t* __restrict__ Abig) {
  int tid = blockIdx.x * 256 + threadIdx.x;     // B_*COMP_/4 threads
  float4 a = ((const float4*)p0)[tid];
  float4 b = ((const float4*)p1)[tid];
  int row = tid >> 8;                           // 256 float4 per row
  int c4 = tid & 255;
  union { ushort_t u[4]; uint2 v; } w;
  w.u[0] = f2b(a.x + b.x);
  w.u[1] = f2b(a.y + b.y);
  w.u[2] = f2b(a.z + b.z);
  w.u[3] = f2b(a.w + b.w);
  *(uint2*)(Abig + (size_t)row * KBIG + IN_ + c4 * 4) = w.v;
}

// ---------------------------------------------------------------------------
// GEMM (proven R0 128x128 structure, 975-993 TF measured): C = A * Bt^T,
// bf16 in, fp32 acc. BK=64, 256 threads = 4 waves 2x2, each wave 4x4 of
// 16x16x32 MFMA per k-sub. Optional split-K (grid = nsplit*num_pid).
//
// R9 changes (index-space only; compute path bit-identical):
//  * T1 XCD-chunked bijective swizzle: physical XCD = orig_bid & 7 (round-
//    robin dispatch); give each XCD a contiguous chunk of work so blocks
//    sharing a B n-panel land on the SAME XCD L2. num_pid % 8 == 0 at both
//    call sites (2048 big, 512 per split small).
//  * column-major work order (m fastest, full-M group): per-XCD concurrent
//    block set = ~2 n-panels x 64 m-tiles -> B working set ~2.6 MB (fits
//    4 MB XCD L2); A panel set (84 MB) is L3-resident across the n-sweep.
//    R0 counters showed FETCH 789 MB vs 126 MB ideal (B re-fetched from
//    HBM ~15x); this targets that directly.
// ---------------------------------------------------------------------------
template <bool BF16_OUT>
__global__ void __launch_bounds__(256, 4) gemm_bt(
    const ushort_t* __restrict__ A, int lda,
    const ushort_t* __restrict__ Bt, int ldb,
    int KS, void* __restrict__ Cp, int ldc, int num_pid_n,
    int num_pid, size_t coff) {
  __shared__ __align__(16) ushort_t As[128 * 64];
  __shared__ __align__(16) ushort_t Bs[128 * 64];
  const int t = threadIdx.x;
  const int wave = t >> 6;
  const int lane = t & 63;
  const int wr = (wave >> 1) * 64;   // wave row offset in tile
  const int wc = (wave & 1) * 64;    // wave col offset in tile
  const int r = lane & 15;
  const int q = lane >> 4;

  // split-K decomposition
  const int s = blockIdx.x / num_pid;
  int rem_all = blockIdx.x - s * num_pid;
  A += (size_t)s * KS;
  Bt += (size_t)s * KS;

  // T1: XCD-chunked bijective swizzle (num_pid % 8 == 0; orig bid & 7 is
  // the physical XCD since splits are 512-aligned)
  rem_all = (rem_all & 7) * (num_pid >> 3) + (rem_all >> 3);

  // column-major work decomposition: m fastest within each n-panel
  const int num_pid_m = num_pid / num_pid_n;    // 64 at both call sites
  const int pid_m = rem_all % num_pid_m;
  const int pid_n = rem_all / num_pid_m;

  // staging addresses: row = rA*32 + wave*8 + (lane>>3), slot = lane&7,
  // global chunk g = slot ^ (row&7)
  const int srow = wave * 8 + (lane >> 3);
  const int gch = (lane & 7) ^ ((lane >> 3) & 7);
  const ushort_t* ga = A + (size_t)(pid_m * 128 + srow) * lda + gch * 8;
  const ushort_t* gb = Bt + (size_t)(pid_n * 128 + srow) * ldb + gch * 8;
  const size_t a32 = (size_t)32 * lda;
  const size_t b32 = (size_t)32 * ldb;

  f32x4 acc[4][4] = {};

  for (int kk = 0; kk < KS; kk += 64) {
    #pragma unroll
    for (int rA = 0; rA < 4; ++rA)
      gll16(ga + rA * a32, As + rA * 2048 + wave * 512);
    #pragma unroll
    for (int rB = 0; rB < 4; ++rB)
      gll16(gb + rB * b32, Bs + rB * 2048 + wave * 512);
    ga += 64;
    gb += 64;
    __syncthreads();   // drains vmcnt (global_load_lds) before ds_read

    #pragma unroll
    for (int ks = 0; ks < 2; ++ks) {
      short8 af[4], bfr[4];
      #pragma unroll
      for (int mi = 0; mi < 4; ++mi) {
        const int row = wr + mi * 16 + r;
        af[mi] = *(const short8*)(As + row * 64 + (((ks * 4 + q) ^ (r & 7)) * 8));
      }
      #pragma unroll
      for (int ni = 0; ni < 4; ++ni) {
        const int row = wc + ni * 16 + r;
        bfr[ni] = *(const short8*)(Bs + row * 64 + (((ks * 4 + q) ^ (r & 7)) * 8));
      }
      #pragma unroll
      for (int mi = 0; mi < 4; ++mi)
        #pragma unroll
        for (int ni = 0; ni < 4; ++ni)
          acc[mi][ni] = __builtin_amdgcn_mfma_f32_16x16x32_bf16(
              af[mi], bfr[ni], acc[mi][ni], 0, 0, 0);
    }
    __syncthreads();   // protect LDS before next stage overwrites
  }

  // C/D layout: col = lane&15, row = (lane>>4)*4 + reg
  const int row0 = pid_m * 128 + wr + q * 4;
  const int col0 = pid_n * 128 + wc + r;
  #pragma unroll
  for (int mi = 0; mi < 4; ++mi) {
    #pragma unroll
    for (int ni = 0; ni < 4; ++ni) {
      const int row = row0 + mi * 16;
      const int col = col0 + ni * 16;
      #pragma unroll
      for (int rr = 0; rr < 4; ++rr) {
        float v = acc[mi][ni][rr];
        if (BF16_OUT)
          ((ushort_t*)Cp)[(size_t)(row + rr) * ldc + col + s * coff] = f2b(v);
        else
          ((float*)Cp)[(size_t)(row + rr) * ldc + col + s * coff] = v;
      }
    }
  }
}

// ---------------------------------------------------------------------------
extern "C" void kernel_launch(void* const* d_in, const int* in_sizes, int n_in,
                              void* d_out, int out_size, void* d_ws, size_t ws_size,
                              hipStream_t stream) {
  const float* x     = (const float*)d_in[0];
  const float* sel   = (const float*)d_in[1];
  const float* We    = (const float*)d_in[2];   // [F,FS,OUT] == [IN][OUT]
  const float* Wcomp = (const float*)d_in[3];   // [COMP][IN]
  const float* Wnet  = (const float*)d_in[4];   // [OUT][COMP]
  float* out = (float*)d_out;

  // workspace layout (bytes): A_big | Mbuf | B_big | Wcb
  char* ws = (char*)d_ws;
  const size_t szAbig = (size_t)B_ * KBIG * 2;     // 83,886,080
  const size_t szMbuf = (size_t)B_ * IN_ * 2;      // 67,108,864
  const size_t szBbig = (size_t)OUT_ * KBIG * 2;   // 41,943,040
  ushort_t* Abig = (ushort_t*)ws;
  ushort_t* Mbuf = (ushort_t*)(ws + szAbig);
  ushort_t* Bbig = (ushort_t*)(ws + szAbig + szMbuf);
  ushort_t* Wcb  = (ushort_t*)(ws + szAbig + szMbuf + szBbig);

  // split-K partials for the small GEMM live in d_out (overwritten by the
  // big GEMM at the end) — 2 x 8192x1024 fp32 = 67 MB of the 134 MB buffer.
  float* part0 = out;
  float* part1 = out + (size_t)B_ * COMP_;

  // 1) gating: scores/softmax -> y (A_big cols 0..4095) and m (Mbuf)
  gate_kernel<<<B_, 256, 0, stream>>>(x, sel, Abig, Mbuf);

  // 2) weight conversion (independent of 1)
  conv_expertT<<<dim3(IN_ / 64, OUT_ / 64), 256, 0, stream>>>(We, Bbig);
  conv_nc<<<(OUT_ * COMP_ + COMP_ * IN_) / (256 * 8), 256, 0, stream>>>(
      Wnet, Wcomp, Bbig, Wcb);

  // 3) compressed = m @ W_comp^T, split-K=2 (grid 1024 -> 4 blk/CU),
  //    fp32 partials into d_out, then reduce -> bf16 A_big cols 4096..5119
  gemm_bt<false><<<2 * (B_ / 128) * (COMP_ / 128), 256, 0, stream>>>(
      Mbuf, IN_, Wcb, IN_, IN_ / 2, (void*)part0, COMP_, COMP_ / 128,
      (B_ / 128) * (COMP_ / 128), (size_t)B_ * COMP_);
  reduce_split<<<(B_ * COMP_) / (256 * 4), 256, 0, stream>>>(part0, part1, Abig);

  // 4) out = [y|compressed] @ [We^T|Wnet]^T  (fused expert + net GEMM)
  gemm_bt<false><<<(B_ / 128) * (OUT_ / 128), 256, 0, stream>>>(
      Abig, KBIG, Bbig, KBIG, KBIG, (void*)out, OUT_, OUT_ / 128,
      (B_ / 128) * (OUT_ / 128), 0);
}

// Round 6
// 751.980 us; speedup vs baseline: 1.0945x; 1.0945x over previous
//
#include <hip/hip_runtime.h>
#include <hip/hip_bf16.h>
#include <cstdint>
#include <cstddef>

// Problem constants
#define B_    8192
#define IN_   4096
#define OUT_  4096
#define F_    16
#define FS_   256
#define COMP_ 1024
#define KBIG  (IN_ + COMP_)   // 5120 fused-K

typedef unsigned short ushort_t;
typedef __attribute__((ext_vector_type(8))) short short8;   // 8 bf16 (4 VGPRs)
typedef __attribute__((ext_vector_type(4))) float f32x4;    // MFMA acc

// fp32 -> bf16 round-to-nearest-even (finite inputs only)
__device__ __forceinline__ ushort_t f2b(float f) {
  unsigned u = __float_as_uint(f);
  u += 0x7fffu + ((u >> 16) & 1u);
  return (ushort_t)(u >> 16);
}

// async global->LDS, 16B per lane; lds dest = wave-uniform base + lane*16
__device__ __forceinline__ void gll16(const void* gp, void* lp) {
  __builtin_amdgcn_global_load_lds(
      (const __attribute__((address_space(1))) unsigned int*)gp,
      (__attribute__((address_space(3))) unsigned int*)lp, 16, 0, 0);
}

// ---------------------------------------------------------------------------
// K1: per-row selector scores -> softmax -> write y (gated) into A_big cols
// [0,4096) and m = x - y into Mbuf, both bf16. One row per 256-thread block.
// ---------------------------------------------------------------------------
__global__ void __launch_bounds__(256) gate_kernel(
    const float* __restrict__ x, const float* __restrict__ sel,
    ushort_t* __restrict__ Abig, ushort_t* __restrict__ Mbuf) {
  const int row = blockIdx.x;
  const int t = threadIdx.x;            // 0..255, 16 elems each
  const float* xr = x + (size_t)row * IN_ + t * 16;
  float4 xv0 = ((const float4*)xr)[0];
  float4 xv1 = ((const float4*)xr)[1];
  float4 xv2 = ((const float4*)xr)[2];
  float4 xv3 = ((const float4*)xr)[3];

  const int f = t >> 4;                 // fragment of this thread
  const int sub = t & 15;
  const float* sp = sel + f * FS_ + sub * 16;
  float4 s0 = ((const float4*)sp)[0];
  float4 s1 = ((const float4*)sp)[1];
  float4 s2 = ((const float4*)sp)[2];
  float4 s3 = ((const float4*)sp)[3];

  float dot = xv0.x * s0.x + xv0.y * s0.y + xv0.z * s0.z + xv0.w * s0.w
            + xv1.x * s1.x + xv1.y * s1.y + xv1.z * s1.z + xv1.w * s1.w
            + xv2.x * s2.x + xv2.y * s2.y + xv2.z * s2.z + xv2.w * s2.w
            + xv3.x * s3.x + xv3.y * s3.y + xv3.z * s3.z + xv3.w * s3.w;

  // reduce across the 16 lanes of this fragment (lane groups are 16-aligned)
  #pragma unroll
  for (int off = 8; off; off >>= 1) dot += __shfl_xor(dot, off, 64);

  __shared__ float sc[F_];
  if (sub == 0) sc[f] = dot;
  __syncthreads();

  float mx = sc[0];
  #pragma unroll
  for (int i = 1; i < F_; ++i) mx = fmaxf(mx, sc[i]);
  float sum = 0.f;
  #pragma unroll
  for (int i = 0; i < F_; ++i) sum += __expf(sc[i] - mx);
  const float p = __expf(sc[f] - mx) / sum;

  float xs[16] = {xv0.x, xv0.y, xv0.z, xv0.w, xv1.x, xv1.y, xv1.z, xv1.w,
                  xv2.x, xv2.y, xv2.z, xv2.w, xv3.x, xv3.y, xv3.z, xv3.w};
  union { ushort_t u[8]; uint4 v; } a0, a1, m0, m1;
  #pragma unroll
  for (int j = 0; j < 8; ++j) {
    float y0 = xs[j] * p;
    float y1 = xs[8 + j] * p;
    a0.u[j] = f2b(y0);
    a1.u[j] = f2b(y1);
    m0.u[j] = f2b(xs[j] - y0);
    m1.u[j] = f2b(xs[8 + j] - y1);
  }
  ushort_t* ap = Abig + (size_t)row * KBIG + t * 16;
  *(uint4*)ap = a0.v;
  *(uint4*)(ap + 8) = a1.v;
  ushort_t* mp = Mbuf + (size_t)row * IN_ + t * 16;
  *(uint4*)mp = m0.v;
  *(uint4*)(mp + 8) = m1.v;
}

// ---------------------------------------------------------------------------
// K2a: expert_weights [IN][OUT] fp32 -> B_big[o][k] bf16 (transposed).
// 64x64 tile via LDS; pad 65 -> <=2-way banking (free).
// ---------------------------------------------------------------------------
__global__ void __launch_bounds__(256) conv_expertT(
    const float* __restrict__ We, ushort_t* __restrict__ Bbig) {
  __shared__ float tile[64][65];
  const int k0 = blockIdx.x * 64;
  const int o0 = blockIdx.y * 64;
  const int t = threadIdx.x;
  const int kr = t >> 4;      // 0..15
  const int oq = t & 15;      // 0..15, float4 column
  #pragma unroll
  for (int rr = 0; rr < 4; ++rr) {
    int k = rr * 16 + kr;
    float4 v = *(const float4*)(We + (size_t)(k0 + k) * OUT_ + o0 + oq * 4);
    tile[k][oq * 4 + 0] = v.x;
    tile[k][oq * 4 + 1] = v.y;
    tile[k][oq * 4 + 2] = v.z;
    tile[k][oq * 4 + 3] = v.w;
  }
  __syncthreads();
  const int kc = t & 7;       // 16B k-chunk
  #pragma unroll
  for (int rr = 0; rr < 2; ++rr) {
    int o = rr * 32 + (t >> 3);
    union { ushort_t u[8]; uint4 v; } w;
    #pragma unroll
    for (int j = 0; j < 8; ++j) w.u[j] = f2b(tile[kc * 8 + j][o]);
    *(uint4*)(Bbig + (size_t)(o0 + o) * KBIG + k0 + kc * 8) = w.v;
  }
}

// K2bc (merged): W_net [OUT][COMP] -> B_big[o][4096+c] bf16  AND
//                W_comp [COMP][IN] -> bf16 flat. 8 elems/thread each.
__global__ void __launch_bounds__(256) conv_nc(
    const float* __restrict__ Wnet, const float* __restrict__ Wc,
    ushort_t* __restrict__ Bbig, ushort_t* __restrict__ Wcb) {
  int tid = blockIdx.x * 256 + threadIdx.x;
  const int NETT = (OUT_ * COMP_) / 8;          // 524288 threads for W_net
  if (tid < NETT) {
    int base = tid * 8;
    int o = base >> 10;
    int c = base & (COMP_ - 1);
    float4 v0 = ((const float4*)(Wnet + base))[0];
    float4 v1 = ((const float4*)(Wnet + base))[1];
    union { ushort_t u[8]; uint4 v; } w;
    w.u[0] = f2b(v0.x); w.u[1] = f2b(v0.y); w.u[2] = f2b(v0.z); w.u[3] = f2b(v0.w);
    w.u[4] = f2b(v1.x); w.u[5] = f2b(v1.y); w.u[6] = f2b(v1.z); w.u[7] = f2b(v1.w);
    *(uint4*)(Bbig + (size_t)o * KBIG + IN_ + c) = w.v;
  } else {
    int base = (tid - NETT) * 8;                // COMP_*IN_/8 threads
    float4 v0 = ((const float4*)(Wc + base))[0];
    float4 v1 = ((const float4*)(Wc + base))[1];
    union { ushort_t u[8]; uint4 v; } w;
    w.u[0] = f2b(v0.x); w.u[1] = f2b(v0.y); w.u[2] = f2b(v0.z); w.u[3] = f2b(v0.w);
    w.u[4] = f2b(v1.x); w.u[5] = f2b(v1.y); w.u[6] = f2b(v1.z); w.u[7] = f2b(v1.w);
    *(uint4*)(Wcb + base) = w.v;
  }
}

// split-K reduce for the small GEMM: compressed = p0 + p1 -> bf16 into
// A_big cols [4096,5120). float4 reads, uint2 (4x bf16) writes.
__global__ void __launch_bounds__(256) reduce_split(
    const float* __restrict__ p0, const float* __restrict__ p1,
    ushort_t* __restrict__ Abig) {
  int tid = blockIdx.x * 256 + threadIdx.x;     // B_*COMP_/4 threads
  float4 a = ((const float4*)p0)[tid];
  float4 b = ((const float4*)p1)[tid];
  int row = tid >> 8;                           // 256 float4 per row
  int c4 = tid & 255;
  union { ushort_t u[4]; uint2 v; } w;
  w.u[0] = f2b(a.x + b.x);
  w.u[1] = f2b(a.y + b.y);
  w.u[2] = f2b(a.z + b.z);
  w.u[3] = f2b(a.w + b.w);
  *(uint2*)(Abig + (size_t)row * KBIG + IN_ + c4 * 4) = w.v;
}

// ---------------------------------------------------------------------------
// GEMM: exact R0 structure (harness-proven 346.6 us on the big call):
// C[M,N] = A[M,K] * Bt[N,K]^T, bf16 in, fp32 acc. 128x128 tile, BK=64,
// 256 threads = 4 waves in 2x2, each wave 4x4 of 16x16x32 MFMA per k-sub.
// Split-K via grid = nsplit*num_pid. GROUP_M=16 supertile work order
// (UNCHANGED from R0 — R5 proved replacing it regresses FETCH 789->1345 MB).
//
// R10's ONLY change: T1 XCD-chunked bijective remap applied to rem_all
// BEFORE the (unchanged) supertile decomposition — m192/m204 recipe.
// Default dispatch round-robins consecutive blocks across the 8 XCDs; the
// remap gives each XCD a CONTIGUOUS range of supertile indices so blocks
// sharing a B panel / A group co-locate on one XCD's 4 MB L2.
// num_pid % 8 == 0 at both call sites (2048 big, 512 per split small).
// ---------------------------------------------------------------------------
template <bool BF16_OUT>
__global__ void __launch_bounds__(256, 4) gemm_bt(
    const ushort_t* __restrict__ A, int lda,
    const ushort_t* __restrict__ Bt, int ldb,
    int KS, void* __restrict__ Cp, int ldc, int num_pid_n,
    int num_pid, size_t coff) {
  __shared__ __align__(16) ushort_t As[128 * 64];
  __shared__ __align__(16) ushort_t Bs[128 * 64];
  const int t = threadIdx.x;
  const int wave = t >> 6;
  const int lane = t & 63;
  const int wr = (wave >> 1) * 64;   // wave row offset in tile
  const int wc = (wave & 1) * 64;    // wave col offset in tile
  const int r = lane & 15;
  const int q = lane >> 4;

  // split-K decomposition
  const int s = blockIdx.x / num_pid;
  int rem_all = blockIdx.x - s * num_pid;
  A += (size_t)s * KS;
  Bt += (size_t)s * KS;

  // T1: XCD-chunked bijective remap (num_pid % 8 == 0). Physical XCD of
  // this block = orig bid % 8 (round-robin dispatch; split boundaries are
  // 512-aligned so parity is preserved). After remap, XCD x owns the
  // contiguous supertile range [x*num_pid/8, (x+1)*num_pid/8).
  rem_all = (rem_all & 7) * (num_pid >> 3) + (rem_all >> 3);

  // grouped supertile swizzle: 16 m-tiles per group, n sweeps within group
  // (exact R0 work order)
  const int pids_per_group = num_pid_n << 4;
  const int group_id = rem_all / pids_per_group;
  const int rem = rem_all - group_id * pids_per_group;
  const int pid_m = (group_id << 4) + (rem & 15);
  const int pid_n = rem >> 4;

  // staging addresses: row = rA*32 + wave*8 + (lane>>3), slot = lane&7,
  // global chunk g = slot ^ (row&7)
  const int srow = wave * 8 + (lane >> 3);
  const int gch = (lane & 7) ^ ((lane >> 3) & 7);
  const ushort_t* ga = A + (size_t)(pid_m * 128 + srow) * lda + gch * 8;
  const ushort_t* gb = Bt + (size_t)(pid_n * 128 + srow) * ldb + gch * 8;
  const size_t a32 = (size_t)32 * lda;
  const size_t b32 = (size_t)32 * ldb;

  f32x4 acc[4][4] = {};

  for (int kk = 0; kk < KS; kk += 64) {
    #pragma unroll
    for (int rA = 0; rA < 4; ++rA)
      gll16(ga + rA * a32, As + rA * 2048 + wave * 512);
    #pragma unroll
    for (int rB = 0; rB < 4; ++rB)
      gll16(gb + rB * b32, Bs + rB * 2048 + wave * 512);
    ga += 64;
    gb += 64;
    __syncthreads();   // drains vmcnt (global_load_lds) before ds_read

    #pragma unroll
    for (int ks = 0; ks < 2; ++ks) {
      short8 af[4], bfr[4];
      #pragma unroll
      for (int mi = 0; mi < 4; ++mi) {
        const int row = wr + mi * 16 + r;
        af[mi] = *(const short8*)(As + row * 64 + (((ks * 4 + q) ^ (r & 7)) * 8));
      }
      #pragma unroll
      for (int ni = 0; ni < 4; ++ni) {
        const int row = wc + ni * 16 + r;
        bfr[ni] = *(const short8*)(Bs + row * 64 + (((ks * 4 + q) ^ (r & 7)) * 8));
      }
      #pragma unroll
      for (int mi = 0; mi < 4; ++mi)
        #pragma unroll
        for (int ni = 0; ni < 4; ++ni)
          acc[mi][ni] = __builtin_amdgcn_mfma_f32_16x16x32_bf16(
              af[mi], bfr[ni], acc[mi][ni], 0, 0, 0);
    }
    __syncthreads();   // protect LDS before next stage overwrites
  }

  // C/D layout: col = lane&15, row = (lane>>4)*4 + reg
  const int row0 = pid_m * 128 + wr + q * 4;
  const int col0 = pid_n * 128 + wc + r;
  #pragma unroll
  for (int mi = 0; mi < 4; ++mi) {
    #pragma unroll
    for (int ni = 0; ni < 4; ++ni) {
      const int row = row0 + mi * 16;
      const int col = col0 + ni * 16;
      #pragma unroll
      for (int rr = 0; rr < 4; ++rr) {
        float v = acc[mi][ni][rr];
        if (BF16_OUT)
          ((ushort_t*)Cp)[(size_t)(row + rr) * ldc + col + s * coff] = f2b(v);
        else
          ((float*)Cp)[(size_t)(row + rr) * ldc + col + s * coff] = v;
      }
    }
  }
}

// ---------------------------------------------------------------------------
extern "C" void kernel_launch(void* const* d_in, const int* in_sizes, int n_in,
                              void* d_out, int out_size, void* d_ws, size_t ws_size,
                              hipStream_t stream) {
  const float* x     = (const float*)d_in[0];
  const float* sel   = (const float*)d_in[1];
  const float* We    = (const float*)d_in[2];   // [F,FS,OUT] == [IN][OUT]
  const float* Wcomp = (const float*)d_in[3];   // [COMP][IN]
  const float* Wnet  = (const float*)d_in[4];   // [OUT][COMP]
  float* out = (float*)d_out;

  // workspace layout (bytes): A_big | Mbuf | B_big | Wcb
  char* ws = (char*)d_ws;
  const size_t szAbig = (size_t)B_ * KBIG * 2;     // 83,886,080
  const size_t szMbuf = (size_t)B_ * IN_ * 2;      // 67,108,864
  const size_t szBbig = (size_t)OUT_ * KBIG * 2;   // 41,943,040
  ushort_t* Abig = (ushort_t*)ws;
  ushort_t* Mbuf = (ushort_t*)(ws + szAbig);
  ushort_t* Bbig = (ushort_t*)(ws + szAbig + szMbuf);
  ushort_t* Wcb  = (ushort_t*)(ws + szAbig + szMbuf + szBbig);

  // split-K partials for the small GEMM live in d_out (overwritten by the
  // big GEMM at the end) — 2 x 8192x1024 fp32 = 67 MB of the 134 MB buffer.
  float* part0 = out;
  float* part1 = out + (size_t)B_ * COMP_;

  // 1) gating: scores/softmax -> y (A_big cols 0..4095) and m (Mbuf)
  gate_kernel<<<B_, 256, 0, stream>>>(x, sel, Abig, Mbuf);

  // 2) weight conversion (independent of 1)
  conv_expertT<<<dim3(IN_ / 64, OUT_ / 64), 256, 0, stream>>>(We, Bbig);
  conv_nc<<<(OUT_ * COMP_ + COMP_ * IN_) / (256 * 8), 256, 0, stream>>>(
      Wnet, Wcomp, Bbig, Wcb);

  // 3) compressed = m @ W_comp^T, split-K=2 (grid 1024 -> 4 blk/CU),
  //    fp32 partials into d_out, then reduce -> bf16 A_big cols 4096..5119
  gemm_bt<false><<<2 * (B_ / 128) * (COMP_ / 128), 256, 0, stream>>>(
      Mbuf, IN_, Wcb, IN_, IN_ / 2, (void*)part0, COMP_, COMP_ / 128,
      (B_ / 128) * (COMP_ / 128), (size_t)B_ * COMP_);
  reduce_split<<<(B_ * COMP_) / (256 * 4), 256, 0, stream>>>(part0, part1, Abig);

  // 4) out = [y|compressed] @ [We^T|Wnet]^T  (fused expert + net GEMM)
  gemm_bt<false><<<(B_ / 128) * (OUT_ / 128), 256, 0, stream>>>(
      Abig, KBIG, Bbig, KBIG, KBIG, (void*)out, OUT_, OUT_ / 128,
      (B_ / 128) * (OUT_ / 128), 0);
}